// Round 7
// baseline (1533.175 us; speedup 1.0000x reference)
//
#include <hip/hip_runtime.h>

// ---- problem constants ----
#define N_MOLS  2000
#define APM     50
#define N_ATOMS 100001
#define N_BONDS 200001
#define MAX_NB  6
#define AF      133
#define BF      147
#define H       300

// ---- padded layout ----
// SB=320 / SF=160: rows are 640/320 bytes = exact 64B-sector multiples -> no
// partial-sector RMW on writes, fully aligned gathers.
#define SB    320
#define SF    160
#define MB_P  200192   // bonds padded to x128 (1564*128)
#define MA_P  100096   // atoms padded to x128 (782*128)
#define SWH   320      // W_h K-extent
#define SWI   160      // W_i
#define SWO   480      // W_o ([amsg 320 | fa 160])

typedef _Float16 f16x8 __attribute__((ext_vector_type(8)));
typedef _Float16 f16x4 __attribute__((ext_vector_type(4)));
typedef float    f32x4 __attribute__((ext_vector_type(4)));
typedef float    f32x2 __attribute__((ext_vector_type(2)));

// ---------------- cast / prep ----------------
__global__ void cast_fb_kernel(const float* __restrict__ src, _Float16* __restrict__ dst) {
    unsigned i = blockIdx.x * blockDim.x + threadIdx.x;
    if (i >= (unsigned)MB_P * SF) return;
    unsigned m = i / SF, k = i % SF;
    dst[i] = (_Float16)((m < N_BONDS && k < BF) ? src[(size_t)m * BF + k] : 0.f);
}
__global__ void cast_fa_kernel(const float* __restrict__ src, _Float16* __restrict__ dst) {
    unsigned i = blockIdx.x * blockDim.x + threadIdx.x;
    if (i >= (unsigned)MA_P * SF) return;
    unsigned m = i / SF, k = i % SF;
    dst[i] = (_Float16)((m < N_ATOMS && k < AF) ? src[(size_t)m * AF + k] : 0.f);
}
// ---- packed-W cast kernels ----
// Layout: Wt[(((kc*20 + ctg)*16 + r16)*4 + quad)*8 + e] = W^T[n = ctg*16+r16][k = kc*32+quad*8+e]
// -> one wave's B-fragment load for (kc, ctg) is a contiguous, fully-coalesced 1 KiB block.
__global__ void cast_wh_kernel(const float* __restrict__ W, _Float16* __restrict__ Wt) {
    int i = blockIdx.x * blockDim.x + threadIdx.x;
    if (i >= 320 * SWH) return;
    const int e = i & 7, quad = (i >> 3) & 3, r16 = (i >> 5) & 15;
    const int rest = i >> 9, ctg = rest % 20, kc = rest / 20;
    const int n = ctg * 16 + r16, k = kc * 32 + quad * 8 + e;
    Wt[i] = (_Float16)((n < H && k < H) ? W[k * H + n] : 0.f);
}
__global__ void cast_wi_kernel(const float* __restrict__ W, _Float16* __restrict__ Wt) {
    int i = blockIdx.x * blockDim.x + threadIdx.x;
    if (i >= 320 * SWI) return;
    const int e = i & 7, quad = (i >> 3) & 3, r16 = (i >> 5) & 15;
    const int rest = i >> 9, ctg = rest % 20, kc = rest / 20;
    const int n = ctg * 16 + r16, k = kc * 32 + quad * 8 + e;
    Wt[i] = (_Float16)((n < H && k < BF) ? W[k * H + n] : 0.f);
}
// A order for output GEMM: [a_message(320) | f_atoms(160)]; W_o rows 0..132 = f_atoms, 133..432 = a_message
__global__ void cast_wo_kernel(const float* __restrict__ W, _Float16* __restrict__ Wt) {
    int i = blockIdx.x * blockDim.x + threadIdx.x;
    if (i >= 320 * SWO) return;
    const int e = i & 7, quad = (i >> 3) & 3, r16 = (i >> 5) & 15;
    const int rest = i >> 9, ctg = rest % 20, kc = rest / 20;
    const int n = ctg * 16 + r16, k = kc * 32 + quad * 8 + e;
    float v = 0.f;
    if (n < H) {
        if (k < 320) { if (k < H) v = W[(AF + k) * H + n]; }
        else         { int rr = k - 320; if (rr < AF) v = W[rr * H + n]; }
    }
    Wt[i] = (_Float16)v;
}

// ---------------- dense GEMM: 128 rows x FULL 320 cols per block (R4 champion) ----------------
// 4 waves: wave = 64 rows x 160 cols (acc[4][10]); full-row output per block.
// W PRE-SWIZZLED in global -> coalesced 1 KiB wave-loads from L2; zero K-loop
// barriers; LDS only for epilogue (20.7 KB). (256,2): tighter bounds spill (R3).
// MODE 0 (I): A1=fb16(SF), K=160 : out8 = fp8(acc), out16 = relu(acc)
// MODE 1 (H): A1=msg(SB),  K=320 : out16 = acc (linear)
// MODE 2 (O): A1=hm(SB) K0..319, A2=fa16(SF) K320..479 : out16 = relu(acc + bias)
template<int NCHUNK, int MODE>
__global__ __launch_bounds__(256, 2) void dgemm_kernel(
    const _Float16* __restrict__ A1, const _Float16* __restrict__ A2,
    const _Float16* __restrict__ Wt, const float* __restrict__ bias,
    _Float16* __restrict__ out16, unsigned char* __restrict__ out8)
{
    __shared__ __align__(16) _Float16 stage[32 * 324];   // 20.7 KB

    const int tid  = threadIdx.x;
    const int lane = tid & 63, wave = tid >> 6;
    const int r16  = lane & 15, quad = lane >> 4;
    const int rowhalf = wave >> 1, colhalf = wave & 1;
    const int row0 = blockIdx.x * 128 + rowhalf * 64;
    const int colb = colhalf * 160;

    f32x4 acc[4][10];
    #pragma unroll
    for (int s = 0; s < 4; ++s)
        #pragma unroll
        for (int ct = 0; ct < 10; ++ct) acc[s][ct] = f32x4{0.f, 0.f, 0.f, 0.f};

    const _Float16* wb = Wt + (size_t)colhalf * 10 * 512 + (r16 * 4 + quad) * 8;

    #pragma unroll
    for (int kc = 0; kc < NCHUNK; ++kc) {
        const _Float16* ap; int kl, sa;
        if (MODE == 2 && kc >= 10) { ap = A2; kl = kc - 10; sa = SF; }
        else                       { ap = A1; kl = kc; sa = (MODE == 0 ? SF : SB); }
        f16x8 a[4];
        #pragma unroll
        for (int s = 0; s < 4; ++s)
            a[s] = *(const f16x8*)(ap + (size_t)(row0 + s * 16 + r16) * sa + kl * 32 + quad * 8);
        #pragma unroll
        for (int ct = 0; ct < 10; ++ct) {
            const f16x8 b = *(const f16x8*)(wb + (size_t)(kc * 20 + ct) * 512);
            #pragma unroll
            for (int s = 0; s < 4; ++s)
                acc[s][ct] = __builtin_amdgcn_mfma_f32_16x16x32_f16(a[s], b, acc[s][ct], 0, 0, 0);
        }
    }

    // ---- epilogue: LDS-staged transpose, coalesced vector stores ----
    #pragma unroll
    for (int p = 0; p < 4; ++p) {
        if ((p >> 1) == rowhalf) {
            const int sb0 = (p & 1) * 2;
            #pragma unroll
            for (int s2 = 0; s2 < 2; ++s2) {
                const int s = sb0 + s2;
                #pragma unroll
                for (int ct = 0; ct < 10; ++ct) {
                    const int col = colb + ct * 16 + r16;
                    const float bv = (MODE == 2 && col < H) ? bias[col] : 0.f;
                    const int lr = s2 * 16 + quad * 4;
                    #pragma unroll
                    for (int e = 0; e < 4; ++e)
                        stage[(lr + e) * 324 + col] = (_Float16)(acc[s][ct][e] + bv);
                }
            }
        }
        __syncthreads();
        #pragma unroll
        for (int i = 0; i < 5; ++i) {
            const int c = tid + i * 256;
            const int row = c / 40, colc = (c % 40) * 8;
            const _Float16* sp = stage + row * 324 + colc;
            const f16x4 vlo = *(const f16x4*)(sp);
            const f16x4 vhi = *(const f16x4*)(sp + 4);
            f16x8 v;
            #pragma unroll
            for (int j = 0; j < 4; ++j) { v[j] = vlo[j]; v[j + 4] = vhi[j]; }
            const size_t off = (size_t)(blockIdx.x * 128 + p * 32 + row) * SB + colc;
            if (MODE == 0) {
                float f[8];
                #pragma unroll
                for (int j = 0; j < 8; ++j) f[j] = (float)v[j];
                int w0 = __builtin_amdgcn_cvt_pk_fp8_f32(f[0], f[1], 0, false);
                w0 = __builtin_amdgcn_cvt_pk_fp8_f32(f[2], f[3], w0, true);
                int w1 = __builtin_amdgcn_cvt_pk_fp8_f32(f[4], f[5], 0, false);
                w1 = __builtin_amdgcn_cvt_pk_fp8_f32(f[6], f[7], w1, true);
                uint2 pk; pk.x = (unsigned int)w0; pk.y = (unsigned int)w1;
                *(uint2*)(out8 + off) = pk;
            }
            if (MODE == 0 || MODE == 2) {
                #pragma unroll
                for (int j = 0; j < 8; ++j)
                    v[j] = (v[j] > (_Float16)0) ? v[j] : (_Float16)0;
            }
            *(f16x8*)(out16 + off) = v;
        }
        if (p < 3) __syncthreads();
    }
}

// ---------------- FUSED update+GEMM: hb_out = relu(inp + hm[b2a] - w*hb[b2revb]) @ W_h ----------------
// R7: 64-bond block, 128 threads (2 waves). PRE-PASS gathers each bond row ONCE
// (full-row coalesced, update_kernel's access pattern), computes the msg row and
// stores to LDS (stride 336 hw -> 16B-aligned b128 frag reads, ~4-way conflicts).
// K-loop = champion structure: A from LDS, packed W direct from L2, no barriers.
// Eliminates msg materialization (128 MB write + 128 MB read per depth) and a
// dispatch. (R5 failed by re-gathering per K-chunk inside the GEMM; gather-once
// fixes the amplification.)
__global__ __launch_bounds__(128) void dgemm_fused_kernel(
    const _Float16* __restrict__ hbp,      // prev hb, gathered via b2revb
    const _Float16* __restrict__ hmp,      // prev hm, gathered via b2a
    const unsigned char* __restrict__ inp8,
    const _Float16* __restrict__ Wt,       // packed W_h
    const int* __restrict__ b2a, const int* __restrict__ b2revb,
    const float* __restrict__ w_bonds,
    _Float16* __restrict__ out16)
{
    __shared__ __align__(16) _Float16 Als[64 * 336];   // 43 KB; reused as epilogue stage

    const int tid  = threadIdx.x;
    const int lane = tid & 63, wave = tid >> 6;        // 2 waves
    const int r16  = lane & 15, quad = lane >> 4;
    const int row0 = blockIdx.x * 64;

    // ---- pre-pass: 32 rows per wave, lanes 0..39 cover 640 B/row ----
    #pragma unroll 4
    for (int i = 0; i < 32; ++i) {
        const int r = wave * 32 + i;
        const int b = row0 + r;
        if (lane < 40) {
            const bool real = b < N_BONDS;
            const int bc = real ? b : 0;
            const int a  = b2a[bc];
            const int rb = b2revb[bc];
            const float w = w_bonds[bc];
            const int h0 = lane * 8;
            const uint2 i8  = *(const uint2*)(inp8 + (size_t)b * SB + h0);
            const f16x8 hmv = *(const f16x8*)(hmp + (size_t)a  * SB + h0);
            const f16x8 hbv = *(const f16x8*)(hbp + (size_t)rb * SB + h0);
            const f32x2 d0 = __builtin_amdgcn_cvt_pk_f32_fp8(i8.x, false);
            const f32x2 d1 = __builtin_amdgcn_cvt_pk_f32_fp8(i8.x, true);
            const f32x2 d2 = __builtin_amdgcn_cvt_pk_f32_fp8(i8.y, false);
            const f32x2 d3 = __builtin_amdgcn_cvt_pk_f32_fp8(i8.y, true);
            const float inpf[8] = {d0[0], d0[1], d1[0], d1[1], d2[0], d2[1], d3[0], d3[1]};
            f16x8 o;
            #pragma unroll
            for (int j = 0; j < 8; ++j) {
                const float v = inpf[j] + (float)hmv[j] - w * (float)hbv[j];
                o[j] = (_Float16)((real && v > 0.f) ? v : 0.f);
            }
            *(f16x8*)(&Als[r * 336 + h0]) = o;
        }
    }
    __syncthreads();

    // ---- K-loop: A from LDS, B packed from L2 ----
    f32x4 acc[4][10];
    #pragma unroll
    for (int s = 0; s < 4; ++s)
        #pragma unroll
        for (int ct = 0; ct < 10; ++ct) acc[s][ct] = f32x4{0.f, 0.f, 0.f, 0.f};

    const _Float16* wb = Wt + (size_t)wave * 10 * 512 + (r16 * 4 + quad) * 8;

    #pragma unroll
    for (int kc = 0; kc < 10; ++kc) {
        f16x8 a[4];
        #pragma unroll
        for (int s = 0; s < 4; ++s)
            a[s] = *(const f16x8*)(&Als[(s * 16 + r16) * 336 + kc * 32 + quad * 8]);
        #pragma unroll
        for (int ct = 0; ct < 10; ++ct) {
            const f16x8 b = *(const f16x8*)(wb + (size_t)(kc * 20 + ct) * 512);
            #pragma unroll
            for (int s = 0; s < 4; ++s)
                acc[s][ct] = __builtin_amdgcn_mfma_f32_16x16x32_f16(a[s], b, acc[s][ct], 0, 0, 0);
        }
    }
    __syncthreads();   // Als dead; reuse as epilogue stage

    // ---- epilogue: 2 passes of 32 rows; linear output (MODE1 semantics) ----
    _Float16* stage = Als;
    #pragma unroll
    for (int p = 0; p < 2; ++p) {
        #pragma unroll
        for (int s2 = 0; s2 < 2; ++s2) {
            const int s = p * 2 + s2;
            #pragma unroll
            for (int ct = 0; ct < 10; ++ct) {
                const int col = wave * 160 + ct * 16 + r16;
                const int lr = s2 * 16 + quad * 4;
                #pragma unroll
                for (int e = 0; e < 4; ++e)
                    stage[(lr + e) * 324 + col] = (_Float16)acc[s][ct][e];
            }
        }
        __syncthreads();
        #pragma unroll
        for (int i = 0; i < 10; ++i) {
            const int c = tid + i * 128;
            const int row = c / 40, colc = (c % 40) * 8;
            const _Float16* sp = stage + row * 324 + colc;
            const f16x4 vlo = *(const f16x4*)(sp);
            const f16x4 vhi = *(const f16x4*)(sp + 4);
            f16x8 v;
            #pragma unroll
            for (int j = 0; j < 4; ++j) { v[j] = vlo[j]; v[j + 4] = vhi[j]; }
            *(f16x8*)(out16 + (size_t)(row0 + p * 32 + row) * SB + colc) = v;
        }
        if (p < 1) __syncthreads();
    }
}

// ---------------- aggregate: dst[a][:] = sum_k w_bonds[a2b[a][k]] * src[a2b[a][k]][:] ----------------
__global__ __launch_bounds__(256, 8) void aggregate_kernel(
    const _Float16* __restrict__ src,
    const int* __restrict__ a2b,
    const float* __restrict__ w_bonds,
    _Float16* __restrict__ dst)
{
    const int lane = threadIdx.x & 63;
    const int a = blockIdx.x * 4 + (threadIdx.x >> 6);
    if (a >= N_ATOMS || lane >= 40) return;
    const int h0 = lane * 8;
    float acc[8] = {0, 0, 0, 0, 0, 0, 0, 0};
    #pragma unroll
    for (int k = 0; k < MAX_NB; ++k) {
        const int b = a2b[a * MAX_NB + k];
        const float w = w_bonds[b];
        const f16x8 m = *(const f16x8*)(src + (size_t)b * SB + h0);
        #pragma unroll
        for (int j = 0; j < 8; ++j) acc[j] += w * (float)m[j];
    }
    f16x8 o;
    #pragma unroll
    for (int j = 0; j < 8; ++j) o[j] = (_Float16)acc[j];
    *(f16x8*)(dst + (size_t)a * SB + h0) = o;
}

// ---------------- bond update: msg[b] = relu(inp[b] + hm[b2a[b]] - w_b * hb[b2revb[b]]) ----------------
__global__ __launch_bounds__(256, 8) void update_kernel(
    const unsigned char* __restrict__ inp8,
    const _Float16* __restrict__ hm,
    const _Float16* __restrict__ hb,
    const int* __restrict__ b2a,
    const int* __restrict__ b2revb,
    const float* __restrict__ w_bonds,
    _Float16* __restrict__ msg)
{
    const int lane = threadIdx.x & 63;
    const int b = blockIdx.x * 4 + (threadIdx.x >> 6);
    if (b >= MB_P || lane >= 40) return;
    const bool real = b < N_BONDS;
    const int bc = real ? b : 0;
    const int a  = b2a[bc];
    const int rb = b2revb[bc];
    const float w = w_bonds[bc];
    const int h0 = lane * 8;
    const uint2 i8  = *(const uint2*)(inp8 + (size_t)b * SB + h0);
    const f16x8 hmv = *(const f16x8*)(hm + (size_t)a  * SB + h0);
    const f16x8 hbv = *(const f16x8*)(hb + (size_t)rb * SB + h0);
    const f32x2 d0 = __builtin_amdgcn_cvt_pk_f32_fp8(i8.x, false);
    const f32x2 d1 = __builtin_amdgcn_cvt_pk_f32_fp8(i8.x, true);
    const f32x2 d2 = __builtin_amdgcn_cvt_pk_f32_fp8(i8.y, false);
    const f32x2 d3 = __builtin_amdgcn_cvt_pk_f32_fp8(i8.y, true);
    const float inpf[8] = {d0[0], d0[1], d1[0], d1[1], d2[0], d2[1], d3[0], d3[1]};
    f16x8 o;
    #pragma unroll
    for (int j = 0; j < 8; ++j) {
        const float v = inpf[j] + (float)hmv[j] - w * (float)hbv[j];
        o[j] = (_Float16)((real && v > 0.f) ? v : 0.f);
    }
    *(f16x8*)(msg + (size_t)b * SB + h0) = o;
}

// ---------------- readout ----------------
__global__ __launch_bounds__(256, 8) void readout_kernel(
    const _Float16* __restrict__ ah,
    const float* __restrict__ w_atoms,
    const float* __restrict__ dop,
    float* __restrict__ out)
{
    const int lane = threadIdx.x & 63;
    const int m = blockIdx.x * 4 + (threadIdx.x >> 6);
    if (m >= N_MOLS || lane >= 40) return;
    const int h0 = lane * 8;
    const int a0 = 1 + m * APM;
    float acc[8] = {0, 0, 0, 0, 0, 0, 0, 0};
    float wsum = 0.f;
    for (int i = 0; i < APM; ++i) {
        const float w = w_atoms[a0 + i];
        wsum += w;
        const f16x8 v = *(const f16x8*)(ah + (size_t)(a0 + i) * SB + h0);
        #pragma unroll
        for (int j = 0; j < 8; ++j) acc[j] += w * (float)v[j];
    }
    const float s = dop[m] / wsum;
    #pragma unroll
    for (int j = 0; j < 8; ++j) {
        const int h = h0 + j;
        if (h < H) out[(size_t)m * H + h] = s * acc[j];
    }
}

// ---------------- launch ----------------
extern "C" void kernel_launch(void* const* d_in, const int* in_sizes, int n_in,
                              void* d_out, int out_size, void* d_ws, size_t ws_size,
                              hipStream_t stream) {
    const float* f_atoms = (const float*)d_in[0];
    const float* f_bonds = (const float*)d_in[1];
    const float* w_atoms = (const float*)d_in[2];
    const float* w_bonds = (const float*)d_in[3];
    const float* dop     = (const float*)d_in[4];
    const float* W_i     = (const float*)d_in[5];
    const float* W_h     = (const float*)d_in[6];
    const float* W_o     = (const float*)d_in[7];
    const float* b_o     = (const float*)d_in[8];
    const int* a2b    = (const int*)d_in[9];
    const int* b2a    = (const int*)d_in[10];
    const int* b2revb = (const int*)d_in[11];
    float* out = (float*)d_out;

    char* p = (char*)d_ws;
    auto alloc = [&](size_t bytes) {
        char* q = p;
        p += ((bytes + 64 + 255) / 256) * 256;
        return q;
    };
    unsigned char* inp8 = (unsigned char*)alloc((size_t)MB_P * SB);          // 64.1 MB
    _Float16* msg  = (_Float16*)alloc((size_t)MB_P * SB * 2);                // 128.1 MB (msg0/hb1/msg3)
    _Float16* hb   = (_Float16*)alloc((size_t)MB_P * SB * 2);                // 128.1 MB (fb16/hb0/hb2/ah)
    _Float16* hm   = (_Float16*)alloc((size_t)MA_P * SB * 2);                // 64.1 MB
    _Float16* Wth  = (_Float16*)alloc((size_t)320 * SWH * 2);
    _Float16* Wti  = (_Float16*)alloc((size_t)320 * SWI * 2);
    _Float16* Wto  = (_Float16*)alloc((size_t)320 * SWO * 2);                // total ~385 MB
    _Float16* fb16 = hb;                    // fb16 (64 MB) lives in hb until hb0 is written
    _Float16* fa16 = (_Float16*)inp8;       // fa16 (32 MB) lives in inp8 after last update
    _Float16* ah   = hb;                    // output-GEMM result reuses dead hb

    if ((size_t)(p - (char*)d_ws) > ws_size) {   // clean failure instead of fault
        hipMemsetAsync(d_out, 0, (size_t)out_size * sizeof(float), stream);
        return;
    }

    // casts
    {
        unsigned n1 = (unsigned)MB_P * SF;
        cast_fb_kernel<<<(n1 + 255) / 256, 256, 0, stream>>>(f_bonds, fb16);
        cast_wh_kernel<<<(320 * SWH + 255) / 256, 256, 0, stream>>>(W_h, Wth);
        cast_wi_kernel<<<(320 * SWI + 255) / 256, 256, 0, stream>>>(W_i, Wti);
        cast_wo_kernel<<<(320 * SWO + 255) / 256, 256, 0, stream>>>(W_o, Wto);
    }

    const int gB = MB_P / 128;            // 1564 (256-thread dgemm)
    const int gF = MB_P / 64;             // 3128 (128-thread fused)
    const int gA = MA_P / 128;            // 782
    const int aggGrid = (N_ATOMS + 3) / 4;
    const int updGrid = MB_P / 4;

    // inp = fb @ W_i (fp8, pre-relu); msg0 = relu(inp) -> msg
    dgemm_kernel<5, 0><<<gB, 256, 0, stream>>>(fb16, nullptr, Wti, nullptr, msg, inp8);
    // d=0: hb0 = msg0 @ W_h -> hb (overwrites consumed fb16)
    dgemm_kernel<10, 1><<<gB, 256, 0, stream>>>(msg, nullptr, Wth, nullptr, hb, nullptr);
    aggregate_kernel<<<aggGrid, 256, 0, stream>>>(hb, a2b, w_bonds, hm);          // hm0
    // d=1 fused: hb1 = relu(inp + hm0[b2a] - w*hb0[b2revb]) @ W_h -> msg (msg0 dead)
    dgemm_fused_kernel<<<gF, 128, 0, stream>>>(hb, hm, inp8, Wth, b2a, b2revb, w_bonds, msg);
    aggregate_kernel<<<aggGrid, 256, 0, stream>>>(msg, a2b, w_bonds, hm);         // hm1
    // d=2 fused: hb2 = relu(inp + hm1[b2a] - w*hb1[b2revb]) @ W_h -> hb (hb0 dead)
    dgemm_fused_kernel<<<gF, 128, 0, stream>>>(msg, hm, inp8, Wth, b2a, b2revb, w_bonds, hb);
    aggregate_kernel<<<aggGrid, 256, 0, stream>>>(hb, a2b, w_bonds, hm);          // hm2
    // final update: msg3 = relu(inp + hm2[b2a] - w*hb2[b2revb]) -> msg (hb1 dead)
    update_kernel<<<updGrid, 256, 0, stream>>>(inp8, hm, hb, b2a, b2revb, w_bonds, msg);
    // final atom aggregation from msg3
    aggregate_kernel<<<aggGrid, 256, 0, stream>>>(msg, a2b, w_bonds, hm);         // hm3
    // fa cast into (dead) inp8 region
    {
        unsigned n2 = (unsigned)MA_P * SF;
        cast_fa_kernel<<<(n2 + 255) / 256, 256, 0, stream>>>(f_atoms, fa16);
    }
    // ah = relu([hm3 | fa] @ W_o + b_o) -> hb (hb2 dead)
    dgemm_kernel<15, 2><<<gA, 256, 0, stream>>>(hm, fa16, Wto, b_o, ah, nullptr);
    readout_kernel<<<(N_MOLS + 3) / 4, 256, 0, stream>>>(ah, w_atoms, dop, out);
}

// Round 8
// 1137.180 us; speedup vs baseline: 1.3482x; 1.3482x over previous
//
#include <hip/hip_runtime.h>

// ---- problem constants ----
#define N_MOLS  2000
#define APM     50
#define N_ATOMS 100001
#define N_BONDS 200001
#define MAX_NB  6
#define AF      133
#define BF      147
#define H       300

// ---- padded layout ----
// SB=320 / SF=160: f16 rows are 640/320 bytes = exact 64B-sector multiples.
// fp8 rows (inp8/msg8) are 320 bytes = 5 sectors.
#define SB    320
#define SF    160
#define MB_P  200192   // bonds padded to x128 (1564*128)
#define MA_P  100096   // atoms padded to x128 (782*128)
#define SWH   320      // W_h K-extent
#define SWI   160      // W_i
#define SWO   480      // W_o ([amsg 320 | fa 160])

typedef _Float16 f16x8 __attribute__((ext_vector_type(8)));
typedef _Float16 f16x4 __attribute__((ext_vector_type(4)));
typedef float    f32x4 __attribute__((ext_vector_type(4)));
typedef float    f32x2 __attribute__((ext_vector_type(2)));

__device__ inline void fp8x8_dec(const uint2 u, float* f) {
    const f32x2 d0 = __builtin_amdgcn_cvt_pk_f32_fp8(u.x, false);
    const f32x2 d1 = __builtin_amdgcn_cvt_pk_f32_fp8(u.x, true);
    const f32x2 d2 = __builtin_amdgcn_cvt_pk_f32_fp8(u.y, false);
    const f32x2 d3 = __builtin_amdgcn_cvt_pk_f32_fp8(u.y, true);
    f[0]=d0[0]; f[1]=d0[1]; f[2]=d1[0]; f[3]=d1[1];
    f[4]=d2[0]; f[5]=d2[1]; f[6]=d3[0]; f[7]=d3[1];
}
__device__ inline uint2 fp8x8_enc(const float* f) {
    int w0 = __builtin_amdgcn_cvt_pk_fp8_f32(f[0], f[1], 0, false);
    w0 = __builtin_amdgcn_cvt_pk_fp8_f32(f[2], f[3], w0, true);
    int w1 = __builtin_amdgcn_cvt_pk_fp8_f32(f[4], f[5], 0, false);
    w1 = __builtin_amdgcn_cvt_pk_fp8_f32(f[6], f[7], w1, true);
    uint2 r; r.x = (unsigned)w0; r.y = (unsigned)w1; return r;
}

// ---------------- cast / prep ----------------
__global__ void cast_fb_kernel(const float* __restrict__ src, _Float16* __restrict__ dst) {
    unsigned i = blockIdx.x * blockDim.x + threadIdx.x;
    if (i >= (unsigned)MB_P * SF) return;
    unsigned m = i / SF, k = i % SF;
    dst[i] = (_Float16)((m < N_BONDS && k < BF) ? src[(size_t)m * BF + k] : 0.f);
}
__global__ void cast_fa_kernel(const float* __restrict__ src, _Float16* __restrict__ dst) {
    unsigned i = blockIdx.x * blockDim.x + threadIdx.x;
    if (i >= (unsigned)MA_P * SF) return;
    unsigned m = i / SF, k = i % SF;
    dst[i] = (_Float16)((m < N_ATOMS && k < AF) ? src[(size_t)m * AF + k] : 0.f);
}
// ---- packed-W cast kernels ----
// Wt[(((kc*20 + ctg)*16 + r16)*4 + quad)*8 + e] = W^T[n = ctg*16+r16][k = kc*32+quad*8+e]
// -> one wave's B-fragment load for (kc, ctg) is a contiguous coalesced 1 KiB block.
__global__ void cast_wh_kernel(const float* __restrict__ W, _Float16* __restrict__ Wt) {
    int i = blockIdx.x * blockDim.x + threadIdx.x;
    if (i >= 320 * SWH) return;
    const int e = i & 7, quad = (i >> 3) & 3, r16 = (i >> 5) & 15;
    const int rest = i >> 9, ctg = rest % 20, kc = rest / 20;
    const int n = ctg * 16 + r16, k = kc * 32 + quad * 8 + e;
    Wt[i] = (_Float16)((n < H && k < H) ? W[k * H + n] : 0.f);
}
__global__ void cast_wi_kernel(const float* __restrict__ W, _Float16* __restrict__ Wt) {
    int i = blockIdx.x * blockDim.x + threadIdx.x;
    if (i >= 320 * SWI) return;
    const int e = i & 7, quad = (i >> 3) & 3, r16 = (i >> 5) & 15;
    const int rest = i >> 9, ctg = rest % 20, kc = rest / 20;
    const int n = ctg * 16 + r16, k = kc * 32 + quad * 8 + e;
    Wt[i] = (_Float16)((n < H && k < BF) ? W[k * H + n] : 0.f);
}
__global__ void cast_wo_kernel(const float* __restrict__ W, _Float16* __restrict__ Wt) {
    int i = blockIdx.x * blockDim.x + threadIdx.x;
    if (i >= 320 * SWO) return;
    const int e = i & 7, quad = (i >> 3) & 3, r16 = (i >> 5) & 15;
    const int rest = i >> 9, ctg = rest % 20, kc = rest / 20;
    const int n = ctg * 16 + r16, k = kc * 32 + quad * 8 + e;
    float v = 0.f;
    if (n < H) {
        if (k < 320) { if (k < H) v = W[(AF + k) * H + n]; }
        else         { int rr = k - 320; if (rr < AF) v = W[rr * H + n]; }
    }
    Wt[i] = (_Float16)v;
}

// ---------------- dense GEMM: 128 rows x FULL 320 cols per block (R4 champion core) ----------------
// 4 waves: wave = 64 rows x 160 cols (acc[4][10]). W PRE-SWIZZLED -> coalesced
// 1 KiB wave-loads from L2; zero K-loop barriers; LDS only for epilogue.
// (256,2): tighter launch bounds spill the 160-AGPR accumulator (R3).
// MODE 0 (I):  A1=fb16(SF), K=160 : out8 = fp8(acc) ONLY (msg0 not materialized)
// MODE 2 (O):  A1=hm(SB) K0..319, A2=fa16(SF) K320..479 : out16 = relu(acc+bias)
// MODE 4 (H0): A8=inp8 fp8, A = relu(dec(inp8))  : out16 = acc (linear hb)
// MODE 5 (H):  A8=msg8 fp8, A = dec(msg8)        : out16 = acc (linear hb)
template<int NCHUNK, int MODE>
__global__ __launch_bounds__(256, 2) void dgemm_kernel(
    const _Float16* __restrict__ A1, const _Float16* __restrict__ A2,
    const unsigned char* __restrict__ A8,
    const _Float16* __restrict__ Wt, const float* __restrict__ bias,
    _Float16* __restrict__ out16, unsigned char* __restrict__ out8)
{
    __shared__ __align__(16) _Float16 stage[32 * 324];   // 20.7 KB

    const int tid  = threadIdx.x;
    const int lane = tid & 63, wave = tid >> 6;
    const int r16  = lane & 15, quad = lane >> 4;
    const int rowhalf = wave >> 1, colhalf = wave & 1;
    const int row0 = blockIdx.x * 128 + rowhalf * 64;
    const int colb = colhalf * 160;

    f32x4 acc[4][10];
    #pragma unroll
    for (int s = 0; s < 4; ++s)
        #pragma unroll
        for (int ct = 0; ct < 10; ++ct) acc[s][ct] = f32x4{0.f, 0.f, 0.f, 0.f};

    const _Float16* wb = Wt + (size_t)colhalf * 10 * 512 + (r16 * 4 + quad) * 8;

    #pragma unroll
    for (int kc = 0; kc < NCHUNK; ++kc) {
        f16x8 a[4];
        if constexpr (MODE == 4 || MODE == 5) {
            #pragma unroll
            for (int s = 0; s < 4; ++s) {
                const uint2 u = *(const uint2*)(A8 + (size_t)(row0 + s * 16 + r16) * 320 + kc * 32 + quad * 8);
                float f[8];
                fp8x8_dec(u, f);
                #pragma unroll
                for (int j = 0; j < 8; ++j) {
                    float v = f[j];
                    if (MODE == 4) v = v > 0.f ? v : 0.f;
                    a[s][j] = (_Float16)v;
                }
            }
        } else {
            const _Float16* ap; int kl, sa;
            if (MODE == 2 && kc >= 10) { ap = A2; kl = kc - 10; sa = SF; }
            else                       { ap = A1; kl = kc; sa = (MODE == 0 ? SF : SB); }
            #pragma unroll
            for (int s = 0; s < 4; ++s)
                a[s] = *(const f16x8*)(ap + (size_t)(row0 + s * 16 + r16) * sa + kl * 32 + quad * 8);
        }
        #pragma unroll
        for (int ct = 0; ct < 10; ++ct) {
            const f16x8 b = *(const f16x8*)(wb + (size_t)(kc * 20 + ct) * 512);
            #pragma unroll
            for (int s = 0; s < 4; ++s)
                acc[s][ct] = __builtin_amdgcn_mfma_f32_16x16x32_f16(a[s], b, acc[s][ct], 0, 0, 0);
        }
    }

    // ---- epilogue: LDS-staged transpose, coalesced vector stores ----
    #pragma unroll
    for (int p = 0; p < 4; ++p) {
        if ((p >> 1) == rowhalf) {
            const int sb0 = (p & 1) * 2;
            #pragma unroll
            for (int s2 = 0; s2 < 2; ++s2) {
                const int s = sb0 + s2;
                #pragma unroll
                for (int ct = 0; ct < 10; ++ct) {
                    const int col = colb + ct * 16 + r16;
                    const float bv = (MODE == 2 && col < H) ? bias[col] : 0.f;
                    const int lr = s2 * 16 + quad * 4;
                    #pragma unroll
                    for (int e = 0; e < 4; ++e)
                        stage[(lr + e) * 324 + col] = (_Float16)(acc[s][ct][e] + bv);
                }
            }
        }
        __syncthreads();
        #pragma unroll
        for (int i = 0; i < 5; ++i) {
            const int c = tid + i * 256;
            const int row = c / 40, colc = (c % 40) * 8;
            const _Float16* sp = stage + row * 324 + colc;
            const f16x4 vlo = *(const f16x4*)(sp);
            const f16x4 vhi = *(const f16x4*)(sp + 4);
            f16x8 v;
            #pragma unroll
            for (int j = 0; j < 4; ++j) { v[j] = vlo[j]; v[j + 4] = vhi[j]; }
            const size_t off = (size_t)(blockIdx.x * 128 + p * 32 + row) * SB + colc;
            if (MODE == 0) {
                float f[8];
                #pragma unroll
                for (int j = 0; j < 8; ++j) f[j] = (float)v[j];
                *(uint2*)(out8 + off) = fp8x8_enc(f);   // pre-relu inp, fp8
            } else {
                if (MODE == 2) {
                    #pragma unroll
                    for (int j = 0; j < 8; ++j)
                        v[j] = (v[j] > (_Float16)0) ? v[j] : (_Float16)0;
                }
                *(f16x8*)(out16 + off) = v;
            }
        }
        if (p < 3) __syncthreads();
    }
}

// ---------------- aggregate (f16 src): hm[a][:] = sum_k w_bonds[a2b[a][k]] * hb[a2b[a][k]][:] ----------------
__global__ __launch_bounds__(256, 8) void aggregate_kernel(
    const _Float16* __restrict__ src,
    const int* __restrict__ a2b,
    const float* __restrict__ w_bonds,
    _Float16* __restrict__ dst)
{
    const int lane = threadIdx.x & 63;
    const int a = blockIdx.x * 4 + (threadIdx.x >> 6);
    if (a >= N_ATOMS || lane >= 40) return;
    const int h0 = lane * 8;
    float acc[8] = {0, 0, 0, 0, 0, 0, 0, 0};
    #pragma unroll
    for (int k = 0; k < MAX_NB; ++k) {
        const int b = a2b[a * MAX_NB + k];
        const float w = w_bonds[b];
        const f16x8 m = *(const f16x8*)(src + (size_t)b * SB + h0);
        #pragma unroll
        for (int j = 0; j < 8; ++j) acc[j] += w * (float)m[j];
    }
    f16x8 o;
    #pragma unroll
    for (int j = 0; j < 8; ++j) o[j] = (_Float16)acc[j];
    *(f16x8*)(dst + (size_t)a * SB + h0) = o;
}

// ---------------- aggregate (fp8 src): final hm from msg8 ----------------
__global__ __launch_bounds__(256, 8) void aggregate8_kernel(
    const unsigned char* __restrict__ src,
    const int* __restrict__ a2b,
    const float* __restrict__ w_bonds,
    _Float16* __restrict__ dst)
{
    const int lane = threadIdx.x & 63;
    const int a = blockIdx.x * 4 + (threadIdx.x >> 6);
    if (a >= N_ATOMS || lane >= 40) return;
    const int h0 = lane * 8;
    float acc[8] = {0, 0, 0, 0, 0, 0, 0, 0};
    #pragma unroll
    for (int k = 0; k < MAX_NB; ++k) {
        const int b = a2b[a * MAX_NB + k];
        const float w = w_bonds[b];
        const uint2 u = *(const uint2*)(src + (size_t)b * 320 + h0);
        float f[8];
        fp8x8_dec(u, f);
        #pragma unroll
        for (int j = 0; j < 8; ++j) acc[j] += w * f[j];
    }
    f16x8 o;
    #pragma unroll
    for (int j = 0; j < 8; ++j) o[j] = (_Float16)acc[j];
    *(f16x8*)(dst + (size_t)a * SB + h0) = o;
}

// ---------------- bond update: msg8[b] = fp8(relu(inp[b] + hm[b2a[b]] - w_b * hb[b2revb[b]])) ----------------
__global__ __launch_bounds__(256, 8) void update_kernel(
    const unsigned char* __restrict__ inp8,
    const _Float16* __restrict__ hm,
    const _Float16* __restrict__ hb,
    const int* __restrict__ b2a,
    const int* __restrict__ b2revb,
    const float* __restrict__ w_bonds,
    unsigned char* __restrict__ msg8)
{
    const int lane = threadIdx.x & 63;
    const int b = blockIdx.x * 4 + (threadIdx.x >> 6);
    if (b >= MB_P || lane >= 40) return;
    const bool real = b < N_BONDS;
    const int bc = real ? b : 0;
    const int a  = b2a[bc];
    const int rb = b2revb[bc];
    const float w = w_bonds[bc];
    const int h0 = lane * 8;
    const uint2 i8  = *(const uint2*)(inp8 + (size_t)b * 320 + h0);
    const f16x8 hmv = *(const f16x8*)(hm + (size_t)a  * SB + h0);
    const f16x8 hbv = *(const f16x8*)(hb + (size_t)rb * SB + h0);
    float inpf[8];
    fp8x8_dec(i8, inpf);
    float o[8];
    #pragma unroll
    for (int j = 0; j < 8; ++j) {
        const float v = inpf[j] + (float)hmv[j] - w * (float)hbv[j];
        o[j] = (real && v > 0.f) ? v : 0.f;
    }
    *(uint2*)(msg8 + (size_t)b * 320 + h0) = fp8x8_enc(o);
}

// ---------------- readout ----------------
__global__ __launch_bounds__(256, 8) void readout_kernel(
    const _Float16* __restrict__ ah,
    const float* __restrict__ w_atoms,
    const float* __restrict__ dop,
    float* __restrict__ out)
{
    const int lane = threadIdx.x & 63;
    const int m = blockIdx.x * 4 + (threadIdx.x >> 6);
    if (m >= N_MOLS || lane >= 40) return;
    const int h0 = lane * 8;
    const int a0 = 1 + m * APM;
    float acc[8] = {0, 0, 0, 0, 0, 0, 0, 0};
    float wsum = 0.f;
    for (int i = 0; i < APM; ++i) {
        const float w = w_atoms[a0 + i];
        wsum += w;
        const f16x8 v = *(const f16x8*)(ah + (size_t)(a0 + i) * SB + h0);
        #pragma unroll
        for (int j = 0; j < 8; ++j) acc[j] += w * (float)v[j];
    }
    const float s = dop[m] / wsum;
    #pragma unroll
    for (int j = 0; j < 8; ++j) {
        const int h = h0 + j;
        if (h < H) out[(size_t)m * H + h] = s * acc[j];
    }
}

// ---------------- launch ----------------
extern "C" void kernel_launch(void* const* d_in, const int* in_sizes, int n_in,
                              void* d_out, int out_size, void* d_ws, size_t ws_size,
                              hipStream_t stream) {
    const float* f_atoms = (const float*)d_in[0];
    const float* f_bonds = (const float*)d_in[1];
    const float* w_atoms = (const float*)d_in[2];
    const float* w_bonds = (const float*)d_in[3];
    const float* dop     = (const float*)d_in[4];
    const float* W_i     = (const float*)d_in[5];
    const float* W_h     = (const float*)d_in[6];
    const float* W_o     = (const float*)d_in[7];
    const float* b_o     = (const float*)d_in[8];
    const int* a2b    = (const int*)d_in[9];
    const int* b2a    = (const int*)d_in[10];
    const int* b2revb = (const int*)d_in[11];
    float* out = (float*)d_out;

    char* p = (char*)d_ws;
    auto alloc = [&](size_t bytes) {
        char* q = p;
        p += ((bytes + 64 + 255) / 256) * 256;
        return q;
    };
    unsigned char* inp8 = (unsigned char*)alloc((size_t)MB_P * 320);         // 64.1 MB
    unsigned char* msg8 = (unsigned char*)alloc((size_t)MB_P * 320);         // 64.1 MB
    _Float16* hb   = (_Float16*)alloc((size_t)MB_P * SB * 2);                // 128.1 MB (single, reused)
    _Float16* hm   = (_Float16*)alloc((size_t)MA_P * SB * 2);                // 64.1 MB
    _Float16* Wth  = (_Float16*)alloc((size_t)320 * SWH * 2);
    _Float16* Wti  = (_Float16*)alloc((size_t)320 * SWI * 2);
    _Float16* Wto  = (_Float16*)alloc((size_t)320 * SWO * 2);                // total ~321 MB
    _Float16* fb16 = hb;                    // fb16 (64 MB) lives in hb until hb is first written
    _Float16* fa16 = (_Float16*)inp8;       // fa16 (32 MB) lives in inp8 after last update
    _Float16* ah   = hb;                    // output-GEMM result reuses dead hb

    if ((size_t)(p - (char*)d_ws) > ws_size) {   // clean failure instead of fault
        hipMemsetAsync(d_out, 0, (size_t)out_size * sizeof(float), stream);
        return;
    }

    // casts
    {
        unsigned n1 = (unsigned)MB_P * SF;
        cast_fb_kernel<<<(n1 + 255) / 256, 256, 0, stream>>>(f_bonds, fb16);
        cast_wh_kernel<<<(320 * SWH + 255) / 256, 256, 0, stream>>>(W_h, Wth);
        cast_wi_kernel<<<(320 * SWI + 255) / 256, 256, 0, stream>>>(W_i, Wti);
        cast_wo_kernel<<<(320 * SWO + 255) / 256, 256, 0, stream>>>(W_o, Wto);
    }

    const int gB = MB_P / 128;            // 1564
    const int gA = MA_P / 128;            // 782
    const int aggGrid = (N_ATOMS + 3) / 4;
    const int updGrid = MB_P / 4;

    // inp = fb @ W_i -> inp8 (fp8, pre-relu); msg0 NOT materialized (= relu(inp))
    dgemm_kernel<5, 0><<<gB, 256, 0, stream>>>(fb16, nullptr, nullptr, Wti, nullptr, nullptr, inp8);
    // d=0: hb = relu(dec(inp8)) @ W_h   (MODE 4; overwrites consumed fb16)
    dgemm_kernel<10, 4><<<gB, 256, 0, stream>>>(nullptr, nullptr, inp8, Wth, nullptr, hb, nullptr);
    aggregate_kernel<<<aggGrid, 256, 0, stream>>>(hb, a2b, w_bonds, hm);
    update_kernel<<<updGrid, 256, 0, stream>>>(inp8, hm, hb, b2a, b2revb, w_bonds, msg8);  // msg1
    // d=1: hb = dec(msg8) @ W_h   (MODE 5)
    dgemm_kernel<10, 5><<<gB, 256, 0, stream>>>(nullptr, nullptr, msg8, Wth, nullptr, hb, nullptr);
    aggregate_kernel<<<aggGrid, 256, 0, stream>>>(hb, a2b, w_bonds, hm);
    update_kernel<<<updGrid, 256, 0, stream>>>(inp8, hm, hb, b2a, b2revb, w_bonds, msg8);  // msg2
    // d=2
    dgemm_kernel<10, 5><<<gB, 256, 0, stream>>>(nullptr, nullptr, msg8, Wth, nullptr, hb, nullptr);
    aggregate_kernel<<<aggGrid, 256, 0, stream>>>(hb, a2b, w_bonds, hm);
    update_kernel<<<updGrid, 256, 0, stream>>>(inp8, hm, hb, b2a, b2revb, w_bonds, msg8);  // msg3
    // final atom aggregation from msg3 (fp8)
    aggregate8_kernel<<<aggGrid, 256, 0, stream>>>(msg8, a2b, w_bonds, hm);
    // fa cast into (dead) inp8 region
    {
        unsigned n2 = (unsigned)MA_P * SF;
        cast_fa_kernel<<<(n2 + 255) / 256, 256, 0, stream>>>(f_atoms, fa16);
    }
    // ah = relu([hm | fa] @ W_o + b_o) -> hb (dead)
    dgemm_kernel<15, 2><<<gA, 256, 0, stream>>>(hm, fa16, nullptr, Wto, b_o, ah, nullptr);
    readout_kernel<<<(N_MOLS + 3) / 4, 256, 0, stream>>>(ah, w_atoms, dop, out);
}

// Round 9
// 1103.831 us; speedup vs baseline: 1.3890x; 1.0302x over previous
//
#include <hip/hip_runtime.h>

// ---- problem constants ----
#define N_MOLS  2000
#define APM     50
#define N_ATOMS 100001
#define N_BONDS 200001
#define MAX_NB  6
#define AF      133
#define BF      147
#define H       300

// ---- padded layout ----
#define SB    320
#define SF    160
#define MB_P  200192   // bonds padded to x128 (1564*128)
#define MA_P  100096   // atoms padded to x128 (782*128)
#define SWH   320
#define SWI   160
#define SWO   480

typedef _Float16 f16x8 __attribute__((ext_vector_type(8)));
typedef _Float16 f16x4 __attribute__((ext_vector_type(4)));
typedef float    f32x4 __attribute__((ext_vector_type(4)));
typedef float    f32x2 __attribute__((ext_vector_type(2)));

__device__ inline void fp8x8_dec(const uint2 u, float* f) {
    const f32x2 d0 = __builtin_amdgcn_cvt_pk_f32_fp8(u.x, false);
    const f32x2 d1 = __builtin_amdgcn_cvt_pk_f32_fp8(u.x, true);
    const f32x2 d2 = __builtin_amdgcn_cvt_pk_f32_fp8(u.y, false);
    const f32x2 d3 = __builtin_amdgcn_cvt_pk_f32_fp8(u.y, true);
    f[0]=d0[0]; f[1]=d0[1]; f[2]=d1[0]; f[3]=d1[1];
    f[4]=d2[0]; f[5]=d2[1]; f[6]=d3[0]; f[7]=d3[1];
}
__device__ inline uint2 fp8x8_enc(const float* f) {
    int w0 = __builtin_amdgcn_cvt_pk_fp8_f32(f[0], f[1], 0, false);
    w0 = __builtin_amdgcn_cvt_pk_fp8_f32(f[2], f[3], w0, true);
    int w1 = __builtin_amdgcn_cvt_pk_fp8_f32(f[4], f[5], 0, false);
    w1 = __builtin_amdgcn_cvt_pk_fp8_f32(f[6], f[7], w1, true);
    uint2 r; r.x = (unsigned)w0; r.y = (unsigned)w1; return r;
}

// ---------------- cast / prep ----------------
__global__ void cast_fb_kernel(const float* __restrict__ src, _Float16* __restrict__ dst) {
    unsigned i = blockIdx.x * blockDim.x + threadIdx.x;
    if (i >= (unsigned)MB_P * SF) return;
    unsigned m = i / SF, k = i % SF;
    dst[i] = (_Float16)((m < N_BONDS && k < BF) ? src[(size_t)m * BF + k] : 0.f);
}
__global__ void cast_fa_kernel(const float* __restrict__ src, _Float16* __restrict__ dst) {
    unsigned i = blockIdx.x * blockDim.x + threadIdx.x;
    if (i >= (unsigned)MA_P * SF) return;
    unsigned m = i / SF, k = i % SF;
    dst[i] = (_Float16)((m < N_ATOMS && k < AF) ? src[(size_t)m * AF + k] : 0.f);
}
// packed-W: Wt[(((kc*20 + ctg)*16 + r16)*4 + quad)*8 + e] = W^T[n=ctg*16+r16][k=kc*32+quad*8+e]
__global__ void cast_wh_kernel(const float* __restrict__ W, _Float16* __restrict__ Wt) {
    int i = blockIdx.x * blockDim.x + threadIdx.x;
    if (i >= 320 * SWH) return;
    const int e = i & 7, quad = (i >> 3) & 3, r16 = (i >> 5) & 15;
    const int rest = i >> 9, ctg = rest % 20, kc = rest / 20;
    const int n = ctg * 16 + r16, k = kc * 32 + quad * 8 + e;
    Wt[i] = (_Float16)((n < H && k < H) ? W[k * H + n] : 0.f);
}
__global__ void cast_wi_kernel(const float* __restrict__ W, _Float16* __restrict__ Wt) {
    int i = blockIdx.x * blockDim.x + threadIdx.x;
    if (i >= 320 * SWI) return;
    const int e = i & 7, quad = (i >> 3) & 3, r16 = (i >> 5) & 15;
    const int rest = i >> 9, ctg = rest % 20, kc = rest / 20;
    const int n = ctg * 16 + r16, k = kc * 32 + quad * 8 + e;
    Wt[i] = (_Float16)((n < H && k < BF) ? W[k * H + n] : 0.f);
}
__global__ void cast_wo_kernel(const float* __restrict__ W, _Float16* __restrict__ Wt) {
    int i = blockIdx.x * blockDim.x + threadIdx.x;
    if (i >= 320 * SWO) return;
    const int e = i & 7, quad = (i >> 3) & 3, r16 = (i >> 5) & 15;
    const int rest = i >> 9, ctg = rest % 20, kc = rest / 20;
    const int n = ctg * 16 + r16, k = kc * 32 + quad * 8 + e;
    float v = 0.f;
    if (n < H) {
        if (k < 320) { if (k < H) v = W[(AF + k) * H + n]; }
        else         { int rr = k - 320; if (rr < AF) v = W[rr * H + n]; }
    }
    Wt[i] = (_Float16)v;
}

// ---------------- dense GEMM (f16 A): 128 rows x 320 cols per block ----------------
// MODE 0 (I): A1=fb16(SF), K=160 : out8 = fp8(acc) only (msg0 = relu(inp) not materialized)
// MODE 2 (O): A1=hm(SB) K0..319, A2=fa16(SF) K320..479 : out16 = relu(acc+bias)
template<int NCHUNK, int MODE>
__global__ __launch_bounds__(256, 2) void dgemm_kernel(
    const _Float16* __restrict__ A1, const _Float16* __restrict__ A2,
    const _Float16* __restrict__ Wt, const float* __restrict__ bias,
    _Float16* __restrict__ out16, unsigned char* __restrict__ out8)
{
    __shared__ __align__(16) _Float16 stage[32 * 324];   // 20.7 KB

    const int tid  = threadIdx.x;
    const int lane = tid & 63, wave = tid >> 6;
    const int r16  = lane & 15, quad = lane >> 4;
    const int rowhalf = wave >> 1, colhalf = wave & 1;
    const int row0 = blockIdx.x * 128 + rowhalf * 64;
    const int colb = colhalf * 160;

    f32x4 acc[4][10];
    #pragma unroll
    for (int s = 0; s < 4; ++s)
        #pragma unroll
        for (int ct = 0; ct < 10; ++ct) acc[s][ct] = f32x4{0.f, 0.f, 0.f, 0.f};

    const _Float16* wb = Wt + (size_t)colhalf * 10 * 512 + (r16 * 4 + quad) * 8;

    #pragma unroll
    for (int kc = 0; kc < NCHUNK; ++kc) {
        const _Float16* ap; int kl, sa;
        if (MODE == 2 && kc >= 10) { ap = A2; kl = kc - 10; sa = SF; }
        else                       { ap = A1; kl = kc; sa = (MODE == 0 ? SF : SB); }
        f16x8 a[4];
        #pragma unroll
        for (int s = 0; s < 4; ++s)
            a[s] = *(const f16x8*)(ap + (size_t)(row0 + s * 16 + r16) * sa + kl * 32 + quad * 8);
        #pragma unroll
        for (int ct = 0; ct < 10; ++ct) {
            const f16x8 b = *(const f16x8*)(wb + (size_t)(kc * 20 + ct) * 512);
            #pragma unroll
            for (int s = 0; s < 4; ++s)
                acc[s][ct] = __builtin_amdgcn_mfma_f32_16x16x32_f16(a[s], b, acc[s][ct], 0, 0, 0);
        }
    }

    #pragma unroll
    for (int p = 0; p < 4; ++p) {
        if ((p >> 1) == rowhalf) {
            const int sb0 = (p & 1) * 2;
            #pragma unroll
            for (int s2 = 0; s2 < 2; ++s2) {
                const int s = sb0 + s2;
                #pragma unroll
                for (int ct = 0; ct < 10; ++ct) {
                    const int col = colb + ct * 16 + r16;
                    const float bv = (MODE == 2 && col < H) ? bias[col] : 0.f;
                    const int lr = s2 * 16 + quad * 4;
                    #pragma unroll
                    for (int e = 0; e < 4; ++e)
                        stage[(lr + e) * 324 + col] = (_Float16)(acc[s][ct][e] + bv);
                }
            }
        }
        __syncthreads();
        #pragma unroll
        for (int i = 0; i < 5; ++i) {
            const int c = tid + i * 256;
            const int row = c / 40, colc = (c % 40) * 8;
            const _Float16* sp = stage + row * 324 + colc;
            const f16x4 vlo = *(const f16x4*)(sp);
            const f16x4 vhi = *(const f16x4*)(sp + 4);
            f16x8 v;
            #pragma unroll
            for (int j = 0; j < 4; ++j) { v[j] = vlo[j]; v[j + 4] = vhi[j]; }
            const size_t off = (size_t)(blockIdx.x * 128 + p * 32 + row) * SB + colc;
            if (MODE == 0) {
                float f[8];
                #pragma unroll
                for (int j = 0; j < 8; ++j) f[j] = (float)v[j];
                *(uint2*)(out8 + off) = fp8x8_enc(f);   // pre-relu inp, fp8
            } else {
                #pragma unroll
                for (int j = 0; j < 8; ++j)
                    v[j] = (v[j] > (_Float16)0) ? v[j] : (_Float16)0;
                *(f16x8*)(out16 + off) = v;
            }
        }
        if (p < 3) __syncthreads();
    }
}

// ---------------- fp8-A GEMM with LDS-staged A-tile (R9) ----------------
// hb = dec(A8) @ W_h (RELU: relu(dec) for the inp8->hb0 layer).
// The block's A-tile is CONTIGUOUS 128x320B = 40 KB -> reg-stage it into LDS
// (10x16B fully-coalesced loads/thread, deep MLP burst), rows padded to 328 B
// (82 words; 82%32=18 -> the 16 fragment rows hit 16 distinct even banks, ~2
// lanes/bank = free). K-loop then reads A from LDS (zero global A latency on
// the critical path) + packed W from L2. LDS 41.98+20.7 KB -> 2 blocks/CU.
template<int RELU>
__global__ __launch_bounds__(256, 2) void dgemm8_kernel(
    const unsigned char* __restrict__ A8,
    const _Float16* __restrict__ Wt,
    _Float16* __restrict__ out16)
{
    __shared__ __align__(16) unsigned char Als[128 * 328];   // 41984 B
    __shared__ __align__(16) _Float16 stage[32 * 324];       // 20736 B

    const int tid  = threadIdx.x;
    const int lane = tid & 63, wave = tid >> 6;
    const int r16  = lane & 15, quad = lane >> 4;
    const int rowhalf = wave >> 1, colhalf = wave & 1;
    const int colb = colhalf * 160;
    const size_t gbase = (size_t)blockIdx.x * 128 * 320;

    // stage A-tile: 2560 chunks of 16B, 10 per thread, fully coalesced
    #pragma unroll
    for (int i = 0; i < 10; ++i) {
        const int idx = tid + i * 256;
        const int row = idx / 20, col = idx % 20;
        const uint4 v = *(const uint4*)(A8 + gbase + (size_t)idx * 16);
        *(uint4*)(&Als[row * 328 + col * 16]) = v;
    }
    __syncthreads();

    f32x4 acc[4][10];
    #pragma unroll
    for (int s = 0; s < 4; ++s)
        #pragma unroll
        for (int ct = 0; ct < 10; ++ct) acc[s][ct] = f32x4{0.f, 0.f, 0.f, 0.f};

    const _Float16* wb = Wt + (size_t)colhalf * 10 * 512 + (r16 * 4 + quad) * 8;

    #pragma unroll
    for (int kc = 0; kc < 10; ++kc) {
        f16x8 a[4];
        #pragma unroll
        for (int s = 0; s < 4; ++s) {
            const int lrow = rowhalf * 64 + s * 16 + r16;
            const uint2 u = *(const uint2*)(&Als[lrow * 328 + kc * 32 + quad * 8]);
            float f[8];
            fp8x8_dec(u, f);
            #pragma unroll
            for (int j = 0; j < 8; ++j) {
                float v = f[j];
                if (RELU) v = v > 0.f ? v : 0.f;
                a[s][j] = (_Float16)v;
            }
        }
        #pragma unroll
        for (int ct = 0; ct < 10; ++ct) {
            const f16x8 b = *(const f16x8*)(wb + (size_t)(kc * 20 + ct) * 512);
            #pragma unroll
            for (int s = 0; s < 4; ++s)
                acc[s][ct] = __builtin_amdgcn_mfma_f32_16x16x32_f16(a[s], b, acc[s][ct], 0, 0, 0);
        }
    }

    // epilogue: linear f16 out (hb)
    #pragma unroll
    for (int p = 0; p < 4; ++p) {
        if ((p >> 1) == rowhalf) {
            const int sb0 = (p & 1) * 2;
            #pragma unroll
            for (int s2 = 0; s2 < 2; ++s2) {
                const int s = sb0 + s2;
                #pragma unroll
                for (int ct = 0; ct < 10; ++ct) {
                    const int col = colb + ct * 16 + r16;
                    const int lr = s2 * 16 + quad * 4;
                    #pragma unroll
                    for (int e = 0; e < 4; ++e)
                        stage[(lr + e) * 324 + col] = (_Float16)acc[s][ct][e];
                }
            }
        }
        __syncthreads();
        #pragma unroll
        for (int i = 0; i < 5; ++i) {
            const int c = tid + i * 256;
            const int row = c / 40, colc = (c % 40) * 8;
            const _Float16* sp = stage + row * 324 + colc;
            const f16x4 vlo = *(const f16x4*)(sp);
            const f16x4 vhi = *(const f16x4*)(sp + 4);
            f16x8 v;
            #pragma unroll
            for (int j = 0; j < 4; ++j) { v[j] = vlo[j]; v[j + 4] = vhi[j]; }
            *(f16x8*)(out16 + (size_t)(blockIdx.x * 128 + p * 32 + row) * SB + colc) = v;
        }
        if (p < 3) __syncthreads();
    }
}

// ---------------- aggregate (f16 src, full-lane): hm[a] = sum_k w*hb[a2b[a][k]] ----------------
__global__ __launch_bounds__(256, 8) void aggregate_kernel(
    const _Float16* __restrict__ src,
    const int* __restrict__ a2b,
    const float* __restrict__ w_bonds,
    _Float16* __restrict__ dst)
{
    const unsigned idx = blockIdx.x * 256 + threadIdx.x;
    if (idx >= (unsigned)N_ATOMS * 40) return;
    const int a = idx / 40, c = idx % 40;
    const int h0 = c * 8;
    float acc[8] = {0, 0, 0, 0, 0, 0, 0, 0};
    #pragma unroll
    for (int k = 0; k < MAX_NB; ++k) {
        const int b = a2b[a * MAX_NB + k];
        const float w = w_bonds[b];
        const f16x8 m = *(const f16x8*)(src + (size_t)b * SB + h0);
        #pragma unroll
        for (int j = 0; j < 8; ++j) acc[j] += w * (float)m[j];
    }
    f16x8 o;
    #pragma unroll
    for (int j = 0; j < 8; ++j) o[j] = (_Float16)acc[j];
    *(f16x8*)(dst + (size_t)a * SB + h0) = o;
}

// ---------------- aggregate (fp8 src, full-lane): final hm from msg8 ----------------
__global__ __launch_bounds__(256, 8) void aggregate8_kernel(
    const unsigned char* __restrict__ src,
    const int* __restrict__ a2b,
    const float* __restrict__ w_bonds,
    _Float16* __restrict__ dst)
{
    const unsigned idx = blockIdx.x * 256 + threadIdx.x;
    if (idx >= (unsigned)N_ATOMS * 40) return;
    const int a = idx / 40, c = idx % 40;
    const int h0 = c * 8;
    float acc[8] = {0, 0, 0, 0, 0, 0, 0, 0};
    #pragma unroll
    for (int k = 0; k < MAX_NB; ++k) {
        const int b = a2b[a * MAX_NB + k];
        const float w = w_bonds[b];
        const uint2 u = *(const uint2*)(src + (size_t)b * 320 + h0);
        float f[8];
        fp8x8_dec(u, f);
        #pragma unroll
        for (int j = 0; j < 8; ++j) acc[j] += w * f[j];
    }
    f16x8 o;
    #pragma unroll
    for (int j = 0; j < 8; ++j) o[j] = (_Float16)acc[j];
    *(f16x8*)(dst + (size_t)a * SB + h0) = o;
}

// ---------------- bond update (full-lane): msg8[b] = fp8(relu(inp + hm[b2a] - w*hb[b2revb])) ----------------
__global__ __launch_bounds__(256, 8) void update_kernel(
    const unsigned char* __restrict__ inp8,
    const _Float16* __restrict__ hm,
    const _Float16* __restrict__ hb,
    const int* __restrict__ b2a,
    const int* __restrict__ b2revb,
    const float* __restrict__ w_bonds,
    unsigned char* __restrict__ msg8)
{
    const unsigned idx = blockIdx.x * 256 + threadIdx.x;
    if (idx >= (unsigned)MB_P * 40) return;
    const int b = idx / 40, c = idx % 40;
    const bool real = b < N_BONDS;
    const int bc = real ? b : 0;
    const int a  = b2a[bc];
    const int rb = b2revb[bc];
    const float w = w_bonds[bc];
    const int h0 = c * 8;
    const uint2 i8  = *(const uint2*)(inp8 + (size_t)b * 320 + h0);
    const f16x8 hmv = *(const f16x8*)(hm + (size_t)a  * SB + h0);
    const f16x8 hbv = *(const f16x8*)(hb + (size_t)rb * SB + h0);
    float inpf[8];
    fp8x8_dec(i8, inpf);
    float o[8];
    #pragma unroll
    for (int j = 0; j < 8; ++j) {
        const float v = inpf[j] + (float)hmv[j] - w * (float)hbv[j];
        o[j] = (real && v > 0.f) ? v : 0.f;
    }
    *(uint2*)(msg8 + (size_t)b * 320 + h0) = fp8x8_enc(o);
}

// ---------------- readout ----------------
__global__ __launch_bounds__(256, 8) void readout_kernel(
    const _Float16* __restrict__ ah,
    const float* __restrict__ w_atoms,
    const float* __restrict__ dop,
    float* __restrict__ out)
{
    const int lane = threadIdx.x & 63;
    const int m = blockIdx.x * 4 + (threadIdx.x >> 6);
    if (m >= N_MOLS || lane >= 40) return;
    const int h0 = lane * 8;
    const int a0 = 1 + m * APM;
    float acc[8] = {0, 0, 0, 0, 0, 0, 0, 0};
    float wsum = 0.f;
    for (int i = 0; i < APM; ++i) {
        const float w = w_atoms[a0 + i];
        wsum += w;
        const f16x8 v = *(const f16x8*)(ah + (size_t)(a0 + i) * SB + h0);
        #pragma unroll
        for (int j = 0; j < 8; ++j) acc[j] += w * (float)v[j];
    }
    const float s = dop[m] / wsum;
    #pragma unroll
    for (int j = 0; j < 8; ++j) {
        const int h = h0 + j;
        if (h < H) out[(size_t)m * H + h] = s * acc[j];
    }
}

// ---------------- launch ----------------
extern "C" void kernel_launch(void* const* d_in, const int* in_sizes, int n_in,
                              void* d_out, int out_size, void* d_ws, size_t ws_size,
                              hipStream_t stream) {
    const float* f_atoms = (const float*)d_in[0];
    const float* f_bonds = (const float*)d_in[1];
    const float* w_atoms = (const float*)d_in[2];
    const float* w_bonds = (const float*)d_in[3];
    const float* dop     = (const float*)d_in[4];
    const float* W_i     = (const float*)d_in[5];
    const float* W_h     = (const float*)d_in[6];
    const float* W_o     = (const float*)d_in[7];
    const float* b_o     = (const float*)d_in[8];
    const int* a2b    = (const int*)d_in[9];
    const int* b2a    = (const int*)d_in[10];
    const int* b2revb = (const int*)d_in[11];
    float* out = (float*)d_out;

    char* p = (char*)d_ws;
    auto alloc = [&](size_t bytes) {
        char* q = p;
        p += ((bytes + 64 + 255) / 256) * 256;
        return q;
    };
    unsigned char* inp8 = (unsigned char*)alloc((size_t)MB_P * 320);         // 64.1 MB
    unsigned char* msg8 = (unsigned char*)alloc((size_t)MB_P * 320);         // 64.1 MB
    _Float16* hb   = (_Float16*)alloc((size_t)MB_P * SB * 2);                // 128.1 MB
    _Float16* hm   = (_Float16*)alloc((size_t)MA_P * SB * 2);                // 64.1 MB
    _Float16* Wth  = (_Float16*)alloc((size_t)320 * SWH * 2);
    _Float16* Wti  = (_Float16*)alloc((size_t)320 * SWI * 2);
    _Float16* Wto  = (_Float16*)alloc((size_t)320 * SWO * 2);                // total ~321 MB
    _Float16* fb16 = hb;                    // fb16 lives in hb until hb is first written
    _Float16* fa16 = (_Float16*)inp8;       // fa16 lives in inp8 after last update
    _Float16* ah   = hb;                    // output-GEMM result reuses dead hb

    if ((size_t)(p - (char*)d_ws) > ws_size) {
        hipMemsetAsync(d_out, 0, (size_t)out_size * sizeof(float), stream);
        return;
    }

    // casts
    {
        unsigned n1 = (unsigned)MB_P * SF;
        cast_fb_kernel<<<(n1 + 255) / 256, 256, 0, stream>>>(f_bonds, fb16);
        cast_wh_kernel<<<(320 * SWH + 255) / 256, 256, 0, stream>>>(W_h, Wth);
        cast_wi_kernel<<<(320 * SWI + 255) / 256, 256, 0, stream>>>(W_i, Wti);
        cast_wo_kernel<<<(320 * SWO + 255) / 256, 256, 0, stream>>>(W_o, Wto);
    }

    const int gB = MB_P / 128;                              // 1564
    const int gA = MA_P / 128;                              // 782
    const int aggGrid = ((unsigned)N_ATOMS * 40 + 255) / 256;   // 15626
    const int updGrid = ((unsigned)MB_P * 40) / 256;            // 31280

    // inp = fb @ W_i -> inp8 (fp8, pre-relu)
    dgemm_kernel<5, 0><<<gB, 256, 0, stream>>>(fb16, nullptr, Wti, nullptr, nullptr, inp8);
    // d=0: hb = relu(dec(inp8)) @ W_h
    dgemm8_kernel<1><<<gB, 256, 0, stream>>>(inp8, Wth, hb);
    aggregate_kernel<<<aggGrid, 256, 0, stream>>>(hb, a2b, w_bonds, hm);
    update_kernel<<<updGrid, 256, 0, stream>>>(inp8, hm, hb, b2a, b2revb, w_bonds, msg8);
    // d=1
    dgemm8_kernel<0><<<gB, 256, 0, stream>>>(msg8, Wth, hb);
    aggregate_kernel<<<aggGrid, 256, 0, stream>>>(hb, a2b, w_bonds, hm);
    update_kernel<<<updGrid, 256, 0, stream>>>(inp8, hm, hb, b2a, b2revb, w_bonds, msg8);
    // d=2
    dgemm8_kernel<0><<<gB, 256, 0, stream>>>(msg8, Wth, hb);
    aggregate_kernel<<<aggGrid, 256, 0, stream>>>(hb, a2b, w_bonds, hm);
    update_kernel<<<updGrid, 256, 0, stream>>>(inp8, hm, hb, b2a, b2revb, w_bonds, msg8);
    // final atom aggregation from msg3 (fp8)
    aggregate8_kernel<<<aggGrid, 256, 0, stream>>>(msg8, a2b, w_bonds, hm);
    // fa cast into (dead) inp8 region
    {
        unsigned n2 = (unsigned)MA_P * SF;
        cast_fa_kernel<<<(n2 + 255) / 256, 256, 0, stream>>>(f_atoms, fa16);
    }
    // ah = relu([hm | fa] @ W_o + b_o)
    dgemm_kernel<15, 2><<<gA, 256, 0, stream>>>(hm, fa16, Wto, b_o, ah, nullptr);
    readout_kernel<<<(N_MOLS + 3) / 4, 256, 0, stream>>>(ah, w_atoms, dop, out);
}